// Round 3
// baseline (468.461 us; speedup 1.0000x reference)
//
#include <hip/hip_runtime.h>
#include <hip/hip_bf16.h>

#define HC 256        // HEADS*OUT_CH
#define NEG_SLOPE 0.2f
#define BM 64
#define BK 64
#define LDK 72        // padded LDS k-stride (bf16 elems): 144B rows, 16B-aligned

typedef short short8_t __attribute__((ext_vector_type(8)));
typedef float float4_t __attribute__((ext_vector_type(4)));
typedef float float2_t __attribute__((ext_vector_type(2)));
typedef int   int4_t   __attribute__((ext_vector_type(4)));

__device__ __forceinline__ unsigned short f2bf(float f) {
  unsigned u = __float_as_uint(f);
  return (unsigned short)((u + 0x7fffu + ((u >> 16) & 1u)) >> 16);  // RNE
}
// bf16 pair unpack from one dword: low half and high half as f32 (1 inst each)
__device__ __forceinline__ float bfLO(unsigned u) { return __uint_as_float(u << 16); }
__device__ __forceinline__ float bfHI(unsigned u) { return __uint_as_float(u & 0xFFFF0000u); }

// ---------------------------------------------------------------------------
// prep: fused  (a) Wt[n][k] = bf16(W[k][n])   (b) deg histogram of dst.
// grid = 256 blocks x 256 threads; block k transposes row k of W and
// processes edge range [k*per, (k+1)*per).
// ---------------------------------------------------------------------------
__global__ __launch_bounds__(256) void prep(
    const float* __restrict__ W, unsigned short* __restrict__ Wt,
    const int* __restrict__ ei, int* __restrict__ deg, int E)
{
  const int k = blockIdx.x;
  const int t = threadIdx.x;
  Wt[t * 256 + k] = f2bf(W[k * 256 + t]);

  const int per = (E + gridDim.x - 1) / gridDim.x;   // 3125
  const int lo = k * per, hi = min(lo + per, E);
  for (int e = lo + t; e < hi; e += 256)
    atomicAdd(&deg[ei[E + e]], 1);
}

// ---------------------------------------------------------------------------
// K1: h = x @ W via bf16 MFMA. Epilogue writes h SLICE-MAJOR:
// h_t[slice][node][32ch], slice = channel>>5 (contiguous 3.2MB per slice ->
// full L2-set utilization for the gather's per-XCD resident plane).
// ---------------------------------------------------------------------------
__global__ __launch_bounds__(256) void gemm_mfma(
    const float* __restrict__ x, const unsigned short* __restrict__ Wt,
    const float* __restrict__ att_src, const float* __restrict__ att_dst,
    unsigned short* __restrict__ h, float* __restrict__ a_src,
    float* __restrict__ a_dst, int nnodes)
{
  __shared__ unsigned short As[BM * LDK];    // 9216 B
  __shared__ unsigned short Bs[256 * LDK];   // 36864 B
  const int t    = threadIdx.x;
  const int wv   = t >> 6;
  const int lane = t & 63;
  const int r0   = blockIdx.x * BM;

  float4_t acc[4][4] = {};   // [mt][nt]

  for (int k0 = 0; k0 < 256; k0 += BK) {
    __syncthreads();
    {
      const int row = t >> 2, kc = (t & 3) * 16;
      const int gr = r0 + row;
      float4 xv[4];
      if (gr < nnodes) {
        const float4* p = (const float4*)(x + (size_t)gr * 256 + k0 + kc);
        xv[0] = p[0]; xv[1] = p[1]; xv[2] = p[2]; xv[3] = p[3];
      } else {
        xv[0] = xv[1] = xv[2] = xv[3] = make_float4(0.f, 0.f, 0.f, 0.f);
      }
      const float* f = (const float*)xv;
      unsigned pk[8];
      #pragma unroll
      for (int i = 0; i < 8; ++i) {
        __hip_bfloat162 b2 = __float22bfloat162_rn(make_float2(f[2 * i], f[2 * i + 1]));
        pk[i] = *(unsigned*)&b2;
      }
      uint4* d = (uint4*)&As[row * LDK + kc];
      d[0] = make_uint4(pk[0], pk[1], pk[2], pk[3]);
      d[1] = make_uint4(pk[4], pk[5], pk[6], pk[7]);
    }
    #pragma unroll
    for (int it = 0; it < 4; ++it) {
      const int n = it * 64 + (t >> 2);
      const int kc = (t & 3) * 16;
      const uint4* g = (const uint4*)(Wt + (size_t)n * 256 + k0 + kc);
      uint4 v0 = g[0], v1 = g[1];
      uint4* d = (uint4*)&Bs[n * LDK + kc];
      d[0] = v0; d[1] = v1;
    }
    __syncthreads();

    #pragma unroll
    for (int ks = 0; ks < 2; ++ks) {
      const int ko = ks * 32 + (lane >> 4) * 8;
      short8_t af[4], bfr[4];
      #pragma unroll
      for (int mt = 0; mt < 4; ++mt)
        af[mt] = *(const short8_t*)&As[(16 * mt + (lane & 15)) * LDK + ko];
      #pragma unroll
      for (int nt = 0; nt < 4; ++nt)
        bfr[nt] = *(const short8_t*)&Bs[(64 * wv + 16 * nt + (lane & 15)) * LDK + ko];
      #pragma unroll
      for (int mt = 0; mt < 4; ++mt)
        #pragma unroll
        for (int nt = 0; nt < 4; ++nt)
          acc[mt][nt] = __builtin_amdgcn_mfma_f32_16x16x32_bf16(
              af[mt], bfr[nt], acc[mt][nt], 0, 0, 0);
    }
  }

  const int q = lane >> 4, l15 = lane & 15;
  const size_t nn32 = (size_t)nnodes * 32;
  float atts[4], attd[4];
  #pragma unroll
  for (int nt = 0; nt < 4; ++nt) {
    atts[nt] = att_src[wv * 64 + 16 * nt + l15];
    attd[nt] = att_dst[wv * 64 + 16 * nt + l15];
  }

  #pragma unroll
  for (int mt = 0; mt < 4; ++mt) {
    #pragma unroll
    for (int reg = 0; reg < 4; ++reg) {
      const int row = r0 + 16 * mt + 4 * q + reg;
      const bool ok = row < nnodes;
      float ps = 0.f, pd = 0.f;
      #pragma unroll
      for (int nt = 0; nt < 4; ++nt) {
        const float v = acc[mt][nt][reg];
        if (ok) {
          const int g2 = 2 * wv + (nt >> 1);          // slice = channel>>5
          const int cc = 16 * (nt & 1) + l15;         // channel&31
          h[(size_t)g2 * nn32 + (size_t)row * 32 + cc] = f2bf(v);
        }
        ps += v * atts[nt];
        pd += v * attd[nt];
      }
      #pragma unroll
      for (int off = 8; off; off >>= 1) {
        ps += __shfl_down(ps, off, 16);
        pd += __shfl_down(pd, off, 16);
      }
      if (ok && l15 == 0) {
        a_src[row * 4 + wv] = ps;
        a_dst[row * 4 + wv] = pd;
      }
    }
  }
}

// ---------------------------------------------------------------------------
// scan_all: single-block exclusive scan of deg -> rowptr, cursor.
// Replaces scan_p1/p2/p3 (3 dispatches -> 1). 1024 threads, each owns a
// contiguous chunk of ~49 nodes: local sum -> block scan -> local rescan.
// ---------------------------------------------------------------------------
__global__ __launch_bounds__(1024) void scan_all(
    const int* __restrict__ deg, int* __restrict__ rowptr,
    int* __restrict__ cursor, int n)
{
  __shared__ int wsum[16], woff[16];
  const int t = threadIdx.x, lane = t & 63, wv = t >> 6;
  const int C = (n + 1023) / 1024;
  const int lo = t * C, hi = min(lo + C, n);

  int s = 0;
  for (int i = lo; i < hi; ++i) s += deg[i];

  int sc = s;
  #pragma unroll
  for (int off = 1; off < 64; off <<= 1) {
    int u = __shfl_up(sc, off, 64);
    if (lane >= off) sc += u;
  }
  if (lane == 63) wsum[wv] = sc;
  __syncthreads();
  if (t == 0) {
    int run = 0;
    #pragma unroll
    for (int i = 0; i < 16; ++i) { int x = wsum[i]; woff[i] = run; run += x; }
    rowptr[n] = run;
  }
  __syncthreads();

  int run = woff[wv] + (sc - s);   // exclusive prefix for this thread's chunk
  for (int i = lo; i < hi; ++i) {
    const int dg = deg[i];
    rowptr[i] = run; cursor[i] = run;
    run += dg;
  }
}

// ---------------------------------------------------------------------------
// fill_csr, XCD-grouped; wexp stored TRANSPOSED as 4 planes wexp[head*E+pos]
// so each gather slice streams 4B/edge.
// ---------------------------------------------------------------------------
__global__ __launch_bounds__(256) void fill_csr(
    const int* __restrict__ ei, const float* __restrict__ a_src,
    const float* __restrict__ a_dst, int* __restrict__ cursor,
    int* __restrict__ csr_src, float* __restrict__ wexp, int E, int nnodes)
{
  const int g    = blockIdx.x & 7;
  const int bg   = blockIdx.x >> 3;
  const int nbg  = gridDim.x >> 3;
  const int gsz  = (nnodes + 7) >> 3;
  const int dlo  = g * gsz;
  const int dhi  = min(dlo + gsz, nnodes);

  for (int e = bg * 256 + threadIdx.x; e < E; e += nbg * 256) {
    const int d = ei[E + e];
    if (d < dlo || d >= dhi) continue;
    const int s = ei[e];
    const int pos = atomicAdd(&cursor[d], 1);
    csr_src[pos] = s;
    const float4 as = ((const float4*)a_src)[s];
    const float4 ad = ((const float4*)a_dst)[d];
    float4 al;
    al.x = as.x + ad.x; al.y = as.y + ad.y;
    al.z = as.z + ad.z; al.w = as.w + ad.w;
    al.x = al.x > 0.f ? al.x : NEG_SLOPE * al.x;
    al.y = al.y > 0.f ? al.y : NEG_SLOPE * al.y;
    al.z = al.z > 0.f ? al.z : NEG_SLOPE * al.z;
    al.w = al.w > 0.f ? al.w : NEG_SLOPE * al.w;
    wexp[pos]         = expf(al.x);
    wexp[E + pos]     = expf(al.y);
    wexp[2 * E + pos] = expf(al.z);
    wexp[3 * E + pos] = expf(al.w);
  }
}

// ---------------------------------------------------------------------------
// K3: gather, channel-sliced (L2-resident h plane per XCD), SUB-PER-DST.
// Group g = blockIdx&7 handles channels [32g,32g+32). Wave = 8 subs of
// 8 lanes; each sub owns ONE dst (4 ch/lane via ushort4). No edge
// partitioning, no cross-lane reduction (dsum is sub-uniform). Edge loop
// software-pipelines the csr/wexp stream loads under the L2-hit h gathers.
// Consecutive subs = consecutive dsts -> contiguous csr/wexp windows.
// ---------------------------------------------------------------------------
__global__ __launch_bounds__(256) void gather_kernel(
    const int* __restrict__ rowptr, const int* __restrict__ csr_src,
    const float* __restrict__ wexp_t, const unsigned short* __restrict__ h,
    const float* __restrict__ a_src, const float* __restrict__ a_dst,
    const float* __restrict__ bias, float* __restrict__ out, int n, int E)
{
  const int g    = blockIdx.x & 7;          // channel slice == XCD
  const int bg   = blockIdx.x >> 3;
  const int wave = threadIdx.x >> 6;
  const int lane = threadIdx.x & 63;
  const int head = g >> 1;
  const int sub  = lane >> 3;               // 8 dsts per wave
  const int co   = (lane & 7) * 4;          // 4 channels per lane
  const int cb   = g * 32 + co;

  const size_t nn32 = (size_t)n * 32;
  const unsigned short* __restrict__ hs = h + (size_t)g * nn32;
  const float* __restrict__ wrow = wexp_t + (size_t)head * E;

  const int d = (bg * 4 + wave) * 8 + sub;  // 2048*4*8 = 65536 slots >= n
  if (d >= n) return;

  const float4 b4 = *(const float4*)&bias[cb];

  // self-loop term
  float alpha = a_src[d * 4 + head] + a_dst[d * 4 + head];
  alpha = alpha > 0.f ? alpha : NEG_SLOPE * alpha;
  const float wself = expf(alpha);
  float dsum = wself;
  float a0, a1, a2, a3;
  {
    const uint2 u = *(const uint2*)&hs[(size_t)d * 32 + co];
    a0 = wself * bfLO(u.x); a1 = wself * bfHI(u.x);
    a2 = wself * bfLO(u.y); a3 = wself * bfHI(u.y);
  }

  int j = rowptr[d];
  const int end = rowptr[d + 1];

  int4_t  sC = {0, 0, 0, 0};
  float4_t wC = {0.f, 0.f, 0.f, 0.f};
  if (j + 3 < end) {
    sC = __builtin_nontemporal_load((const int4_t*)&csr_src[j]);
    wC = __builtin_nontemporal_load((const float4_t*)&wrow[j]);
  }
  while (j + 3 < end) {
    const int jn = j + 4;
    const int jp = (jn + 3 < end) ? jn : j;          // clamp: reload current on last iter
    const int4_t  sN = __builtin_nontemporal_load((const int4_t*)&csr_src[jp]);
    const float4_t wN = __builtin_nontemporal_load((const float4_t*)&wrow[jp]);

    const uint2 u0 = *(const uint2*)&hs[(size_t)sC.x * 32 + co];
    const uint2 u1 = *(const uint2*)&hs[(size_t)sC.y * 32 + co];
    const uint2 u2 = *(const uint2*)&hs[(size_t)sC.z * 32 + co];
    const uint2 u3 = *(const uint2*)&hs[(size_t)sC.w * 32 + co];

    dsum += (wC.x + wC.y) + (wC.z + wC.w);
    a0 += wC.x * bfLO(u0.x) + wC.y * bfLO(u1.x) + wC.z * bfLO(u2.x) + wC.w * bfLO(u3.x);
    a1 += wC.x * bfHI(u0.x) + wC.y * bfHI(u1.x) + wC.z * bfHI(u2.x) + wC.w * bfHI(u3.x);
    a2 += wC.x * bfLO(u0.y) + wC.y * bfLO(u1.y) + wC.z * bfLO(u2.y) + wC.w * bfLO(u3.y);
    a3 += wC.x * bfHI(u0.y) + wC.y * bfHI(u1.y) + wC.z * bfHI(u2.y) + wC.w * bfHI(u3.y);

    sC = sN; wC = wN; j = jn;
  }
  for (; j < end; ++j) {
    const int   s = csr_src[j];
    const float w = wrow[j];
    const uint2 u = *(const uint2*)&hs[(size_t)s * 32 + co];
    dsum += w;
    a0 += w * bfLO(u.x); a1 += w * bfHI(u.x);
    a2 += w * bfLO(u.y); a3 += w * bfHI(u.y);
  }

  const float inv = 1.f / (dsum + 1e-16f);
  float4 o;
  o.x = a0 * inv + b4.x; o.x = o.x > 0.f ? o.x : 0.f;
  o.y = a1 * inv + b4.y; o.y = o.y > 0.f ? o.y : 0.f;
  o.z = a2 * inv + b4.z; o.z = o.z > 0.f ? o.z : 0.f;
  o.w = a3 * inv + b4.w; o.w = o.w > 0.f ? o.w : 0.f;
  __builtin_nontemporal_store(*(const float4_t*)&o,
                              (float4_t*)&out[(size_t)d * 256 + cb]);
}

extern "C" void kernel_launch(void* const* d_in, const int* in_sizes, int n_in,
                              void* d_out, int out_size, void* d_ws, size_t ws_size,
                              hipStream_t stream)
{
  const float* x       = (const float*)d_in[0];
  const int*   ei      = (const int*)d_in[1];
  const float* W       = (const float*)d_in[2];
  const float* att_src = (const float*)d_in[3];
  const float* att_dst = (const float*)d_in[4];
  const float* bias    = (const float*)d_in[5];

  const int nnodes = in_sizes[0] / HC;   // 50000
  const int E      = in_sizes[1] / 2;    // 800000

  float* out = (float*)d_out;
  char* ws = (char*)d_ws;
  // Workspace (~43 MB), all segments 16B-aligned:
  unsigned short* h  = (unsigned short*)ws;                          // nnodes*256 bf16 (slice-major)
  float* a_src = (float*)(ws + (size_t)nnodes * HC * 2);             // nnodes*4 f32
  float* a_dst = a_src + (size_t)nnodes * 4;
  unsigned short* Wt = (unsigned short*)(a_dst + (size_t)nnodes * 4); // 256*256 bf16
  int* deg    = (int*)((char*)Wt + 256 * 256 * 2);                   // nnodes
  int* rowptr = deg + nnodes;                                        // nnodes+1 (pad x4)
  int* cursor = rowptr + ((nnodes + 1 + 3) & ~3);                    // nnodes
  float* wexp = (float*)(cursor + ((nnodes + 3) & ~3));              // 4*E f32 planes (12.8 MB)
  int* csr    = (int*)(wexp + (size_t)4 * E);                        // E

  hipMemsetAsync(deg, 0, (size_t)nnodes * sizeof(int), stream);

  prep<<<256, 256, 0, stream>>>(W, Wt, ei, deg, E);

  gemm_mfma<<<(nnodes + BM - 1) / BM, 256, 0, stream>>>(
      x, Wt, att_src, att_dst, h, a_src, a_dst, nnodes);

  scan_all<<<1, 1024, 0, stream>>>(deg, rowptr, cursor, nnodes);

  fill_csr<<<1024, 256, 0, stream>>>(ei, a_src, a_dst, cursor, csr,
                                     wexp, E, nnodes);

  // 8 slice-groups x 2048 blocks; wave = 8 subs, sub = 1 dst
  gather_kernel<<<8 * 2048, 256, 0, stream>>>(
      rowptr, csr, wexp, h, a_src, a_dst, bias, out, nnodes, E);
}

// Round 5
// 275.019 us; speedup vs baseline: 1.7034x; 1.7034x over previous
//
#include <hip/hip_runtime.h>
#include <hip/hip_bf16.h>

#define HC 256        // HEADS*OUT_CH
#define NEG_SLOPE 0.2f
#define BM 64
#define BK 64
#define LDK 72        // padded LDS k-stride (bf16 elems): 144B rows, 16B-aligned

typedef short short8_t __attribute__((ext_vector_type(8)));
typedef float float4_t __attribute__((ext_vector_type(4)));
typedef int   int4_t   __attribute__((ext_vector_type(4)));

__device__ __forceinline__ unsigned short f2bf(float f) {
  unsigned u = __float_as_uint(f);
  return (unsigned short)((u + 0x7fffu + ((u >> 16) & 1u)) >> 16);  // RNE
}
__device__ __forceinline__ float bf2f(unsigned short b) {
  return __uint_as_float(((unsigned)b) << 16);
}

// ---------------------------------------------------------------------------
// K0: Wt[n][k] = bf16(W[k][n]).  256x256, tiny.
// ---------------------------------------------------------------------------
__global__ void wt_kernel(const float* __restrict__ W, unsigned short* __restrict__ Wt)
{
  const int k = blockIdx.x;
  const int n = threadIdx.x;
  Wt[n * 256 + k] = f2bf(W[k * 256 + n]);
}

// ---------------------------------------------------------------------------
// K1: h = x @ W via bf16 MFMA (exact round-0 version, row-major h).
// ---------------------------------------------------------------------------
__global__ __launch_bounds__(256) void gemm_mfma(
    const float* __restrict__ x, const unsigned short* __restrict__ Wt,
    const float* __restrict__ att_src, const float* __restrict__ att_dst,
    unsigned short* __restrict__ h, float* __restrict__ a_src,
    float* __restrict__ a_dst, int nnodes)
{
  __shared__ unsigned short As[BM * LDK];    // 9216 B
  __shared__ unsigned short Bs[256 * LDK];   // 36864 B
  const int t    = threadIdx.x;
  const int wv   = t >> 6;
  const int lane = t & 63;
  const int r0   = blockIdx.x * BM;

  float4_t acc[4][4] = {};   // [mt][nt]

  for (int k0 = 0; k0 < 256; k0 += BK) {
    __syncthreads();
    {
      const int row = t >> 2, kc = (t & 3) * 16;
      const int gr = r0 + row;
      float4 xv[4];
      if (gr < nnodes) {
        const float4* p = (const float4*)(x + (size_t)gr * 256 + k0 + kc);
        xv[0] = p[0]; xv[1] = p[1]; xv[2] = p[2]; xv[3] = p[3];
      } else {
        xv[0] = xv[1] = xv[2] = xv[3] = make_float4(0.f, 0.f, 0.f, 0.f);
      }
      const float* f = (const float*)xv;
      unsigned pk[8];
      #pragma unroll
      for (int i = 0; i < 8; ++i) {
        __hip_bfloat162 b2 = __float22bfloat162_rn(make_float2(f[2 * i], f[2 * i + 1]));
        pk[i] = *(unsigned*)&b2;
      }
      uint4* d = (uint4*)&As[row * LDK + kc];
      d[0] = make_uint4(pk[0], pk[1], pk[2], pk[3]);
      d[1] = make_uint4(pk[4], pk[5], pk[6], pk[7]);
    }
    #pragma unroll
    for (int it = 0; it < 4; ++it) {
      const int n = it * 64 + (t >> 2);
      const int kc = (t & 3) * 16;
      const uint4* g = (const uint4*)(Wt + (size_t)n * 256 + k0 + kc);
      uint4 v0 = g[0], v1 = g[1];
      uint4* d = (uint4*)&Bs[n * LDK + kc];
      d[0] = v0; d[1] = v1;
    }
    __syncthreads();

    #pragma unroll
    for (int ks = 0; ks < 2; ++ks) {
      const int ko = ks * 32 + (lane >> 4) * 8;
      short8_t af[4], bfr[4];
      #pragma unroll
      for (int mt = 0; mt < 4; ++mt)
        af[mt] = *(const short8_t*)&As[(16 * mt + (lane & 15)) * LDK + ko];
      #pragma unroll
      for (int nt = 0; nt < 4; ++nt)
        bfr[nt] = *(const short8_t*)&Bs[(64 * wv + 16 * nt + (lane & 15)) * LDK + ko];
      #pragma unroll
      for (int mt = 0; mt < 4; ++mt)
        #pragma unroll
        for (int nt = 0; nt < 4; ++nt)
          acc[mt][nt] = __builtin_amdgcn_mfma_f32_16x16x32_bf16(
              af[mt], bfr[nt], acc[mt][nt], 0, 0, 0);
    }
  }

  const int q = lane >> 4, l15 = lane & 15;
  float atts[4], attd[4];
  #pragma unroll
  for (int nt = 0; nt < 4; ++nt) {
    atts[nt] = att_src[wv * 64 + 16 * nt + l15];
    attd[nt] = att_dst[wv * 64 + 16 * nt + l15];
  }

  #pragma unroll
  for (int mt = 0; mt < 4; ++mt) {
    #pragma unroll
    for (int reg = 0; reg < 4; ++reg) {
      const int row = r0 + 16 * mt + 4 * q + reg;
      const bool ok = row < nnodes;
      float ps = 0.f, pd = 0.f;
      #pragma unroll
      for (int nt = 0; nt < 4; ++nt) {
        const float v = acc[mt][nt][reg];
        if (ok) h[(size_t)row * 256 + 64 * wv + 16 * nt + l15] = f2bf(v);
        ps += v * atts[nt];
        pd += v * attd[nt];
      }
      #pragma unroll
      for (int off = 8; off; off >>= 1) {
        ps += __shfl_down(ps, off, 16);
        pd += __shfl_down(pd, off, 16);
      }
      if (ok && l15 == 0) {
        a_src[row * 4 + wv] = ps;
        a_dst[row * 4 + wv] = pd;
      }
    }
  }
}

// ---------------------------------------------------------------------------
// CSR build (round-0 proven versions)
// ---------------------------------------------------------------------------
__global__ void deg_count(const int* __restrict__ ei, int* __restrict__ deg, int E)
{
  const int e = blockIdx.x * blockDim.x + threadIdx.x;
  if (e >= E) return;
  atomicAdd(&deg[ei[E + e]], 1);
}

__global__ __launch_bounds__(256) void scan_p1(const int* __restrict__ deg,
                                               int* __restrict__ bsum, int n)
{
  __shared__ int ws[4];
  const int t = threadIdx.x, lane = t & 63, wv = t >> 6;
  const int base = blockIdx.x * 1024 + t * 4;
  int4 v = make_int4(0, 0, 0, 0);
  if (base + 3 < n) v = *(const int4*)&deg[base];
  else {
    if (base + 0 < n) v.x = deg[base + 0];
    if (base + 1 < n) v.y = deg[base + 1];
    if (base + 2 < n) v.z = deg[base + 2];
  }
  int s = (v.x + v.y) + (v.z + v.w);
  #pragma unroll
  for (int off = 32; off; off >>= 1) s += __shfl_down(s, off, 64);
  if (lane == 0) ws[wv] = s;
  __syncthreads();
  if (t == 0) bsum[blockIdx.x] = (ws[0] + ws[1]) + (ws[2] + ws[3]);
}

__global__ __launch_bounds__(1024) void scan_p2(const int* __restrict__ bsum,
                                                int* __restrict__ boff,
                                                int* __restrict__ rowptr,
                                                int nb, int n)
{
  __shared__ int wsum[16], woff[16];
  const int t = threadIdx.x, lane = t & 63, wv = t >> 6;
  int v = (t < nb) ? bsum[t] : 0;
  int sc = v;
  #pragma unroll
  for (int off = 1; off < 64; off <<= 1) {
    int u = __shfl_up(sc, off, 64);
    if (lane >= off) sc += u;
  }
  if (lane == 63) wsum[wv] = sc;
  __syncthreads();
  if (t == 0) {
    int run = 0;
    #pragma unroll
    for (int i = 0; i < 16; ++i) { int x = wsum[i]; woff[i] = run; run += x; }
    rowptr[n] = run;
  }
  __syncthreads();
  if (t < nb) boff[t] = woff[wv] + sc - v;
}

__global__ __launch_bounds__(256) void scan_p3(const int* __restrict__ deg,
                                               const int* __restrict__ boff,
                                               int* __restrict__ rowptr,
                                               int* __restrict__ cursor, int n)
{
  __shared__ int wsum[4], woff[4];
  const int t = threadIdx.x, lane = t & 63, wv = t >> 6;
  const int base = blockIdx.x * 1024 + t * 4;
  int4 v = make_int4(0, 0, 0, 0);
  if (base + 3 < n) v = *(const int4*)&deg[base];
  else {
    if (base + 0 < n) v.x = deg[base + 0];
    if (base + 1 < n) v.y = deg[base + 1];
    if (base + 2 < n) v.z = deg[base + 2];
  }
  const int s = (v.x + v.y) + (v.z + v.w);
  int sc = s;
  #pragma unroll
  for (int off = 1; off < 64; off <<= 1) {
    int u = __shfl_up(sc, off, 64);
    if (lane >= off) sc += u;
  }
  if (lane == 63) wsum[wv] = sc;
  __syncthreads();
  if (t == 0) {
    int run = 0;
    #pragma unroll
    for (int i = 0; i < 4; ++i) { int x = wsum[i]; woff[i] = run; run += x; }
  }
  __syncthreads();
  int excl = boff[blockIdx.x] + woff[wv] + (sc - s);
  int4 r;
  r.x = excl;
  r.y = r.x + v.x;
  r.z = r.y + v.y;
  r.w = r.z + v.z;
  if (base + 3 < n) {
    *(int4*)&rowptr[base] = r;
    *(int4*)&cursor[base] = r;
  } else {
    if (base + 0 < n) { rowptr[base + 0] = r.x; cursor[base + 0] = r.x; }
    if (base + 1 < n) { rowptr[base + 1] = r.y; cursor[base + 1] = r.y; }
    if (base + 2 < n) { rowptr[base + 2] = r.z; cursor[base + 2] = r.z; }
  }
}

// ---------------------------------------------------------------------------
// fill_csr, XCD-grouped (writeback locality), index-only: the attention
// weight is no longer precomputed (gather computes it inline from a_src/
// a_dst), so this kernel sheds 4 expf + 16B scattered write per edge.
// ---------------------------------------------------------------------------
__global__ __launch_bounds__(256) void fill_csr(
    const int* __restrict__ ei, int* __restrict__ cursor,
    int* __restrict__ csr_src, int E, int nnodes)
{
  const int g    = blockIdx.x & 7;
  const int bg   = blockIdx.x >> 3;
  const int nbg  = gridDim.x >> 3;
  const int gsz  = (nnodes + 7) >> 3;
  const int dlo  = g * gsz;
  const int dhi  = min(dlo + gsz, nnodes);

  for (int e = bg * 256 + threadIdx.x; e < E; e += nbg * 256) {
    const int d = ei[E + e];
    if (d < dlo || d >= dhi) continue;
    const int pos = atomicAdd(&cursor[d], 1);
    csr_src[pos] = ei[e];
  }
}

// ---------------------------------------------------------------------------
// K3: gather — ROUND-0 STRUCTURE (wave-per-dst, full 256ch, 65us proven)
// + two deltas:
//  (1) attention weight computed INLINE from a_src (L2/L3-hot 800KB table)
//      instead of streaming the 12.8MB wexp array.
//  (2) csr int4 software-pipelined (prefetch next iter) so each 4-edge
//      iteration is one memory epoch instead of csr->h serial chain.
// ---------------------------------------------------------------------------
__device__ __forceinline__ float4 ld_h(const unsigned short* __restrict__ h,
                                       int row, int cb)
{
  const ushort4 u = *(const ushort4*)&h[(size_t)row * 256 + cb];
  return make_float4(bf2f(u.x), bf2f(u.y), bf2f(u.z), bf2f(u.w));
}

__device__ __forceinline__ float edge_w(float as, float ad)
{
  float al = as + ad;
  al = al > 0.f ? al : NEG_SLOPE * al;
  return expf(al);
}

__global__ __launch_bounds__(256) void gather_kernel(
    const int* __restrict__ rowptr, const int* __restrict__ csr_src,
    const unsigned short* __restrict__ h,
    const float* __restrict__ a_src, const float* __restrict__ a_dst,
    const float* __restrict__ bias, float* __restrict__ out, int n)
{
  const int wave = threadIdx.x >> 6;
  const int lane = threadIdx.x & 63;
  const int d = blockIdx.x * 4 + wave;
  if (d >= n) return;

  const int head = lane >> 4;
  const int cb   = lane * 4;

  const float ad = a_dst[d * 4 + head];

  // self-loop (weight computed inline; not in csr)
  const float w = edge_w(a_src[d * 4 + head], ad);
  float dsum = w;
  float4 hv = ld_h(h, d, cb);
  float4 acc = make_float4(w * hv.x, w * hv.y, w * hv.z, w * hv.w);

  int j = rowptr[d];
  const int end = rowptr[d + 1];

  int4_t sC = {0, 0, 0, 0};
  if (j + 3 < end)
    sC = __builtin_nontemporal_load((const int4_t*)&csr_src[j]);
  while (j + 3 < end) {
    const int jn = j + 4;
    const int jp = (jn + 3 < end) ? jn : j;   // clamp: reload current on last iter
    const int4_t sN = __builtin_nontemporal_load((const int4_t*)&csr_src[jp]);

    // one epoch: 4 a_src broadcasts + 4 h-row loads, all addressed by sC
    const float as0 = a_src[sC.x * 4 + head];
    const float as1 = a_src[sC.y * 4 + head];
    const float as2 = a_src[sC.z * 4 + head];
    const float as3 = a_src[sC.w * 4 + head];
    const float4 h0 = ld_h(h, sC.x, cb);
    const float4 h1 = ld_h(h, sC.y, cb);
    const float4 h2 = ld_h(h, sC.z, cb);
    const float4 h3 = ld_h(h, sC.w, cb);

    const float w0 = edge_w(as0, ad);
    const float w1 = edge_w(as1, ad);
    const float w2 = edge_w(as2, ad);
    const float w3 = edge_w(as3, ad);

    dsum += (w0 + w1) + (w2 + w3);
    acc.x += w0 * h0.x + w1 * h1.x + w2 * h2.x + w3 * h3.x;
    acc.y += w0 * h0.y + w1 * h1.y + w2 * h2.y + w3 * h3.y;
    acc.z += w0 * h0.z + w1 * h1.z + w2 * h2.z + w3 * h3.z;
    acc.w += w0 * h0.w + w1 * h1.w + w2 * h2.w + w3 * h3.w;

    sC = sN; j = jn;
  }
  for (; j < end; ++j) {
    const int s0 = csr_src[j];
    const float w0 = edge_w(a_src[s0 * 4 + head], ad);
    const float4 h0 = ld_h(h, s0, cb);
    dsum += w0;
    acc.x += w0 * h0.x; acc.y += w0 * h0.y;
    acc.z += w0 * h0.z; acc.w += w0 * h0.w;
  }

  const float inv = 1.f / (dsum + 1e-16f);
  const float4 b4 = ((const float4*)bias)[lane];
  float4 o;
  o.x = acc.x * inv + b4.x; o.x = o.x > 0.f ? o.x : 0.f;
  o.y = acc.y * inv + b4.y; o.y = o.y > 0.f ? o.y : 0.f;
  o.z = acc.z * inv + b4.z; o.z = o.z > 0.f ? o.z : 0.f;
  o.w = acc.w * inv + b4.w; o.w = o.w > 0.f ? o.w : 0.f;
  *(float4*)&out[(size_t)d * 256 + cb] = o;
}

extern "C" void kernel_launch(void* const* d_in, const int* in_sizes, int n_in,
                              void* d_out, int out_size, void* d_ws, size_t ws_size,
                              hipStream_t stream)
{
  const float* x       = (const float*)d_in[0];
  const int*   ei      = (const int*)d_in[1];
  const float* W       = (const float*)d_in[2];
  const float* att_src = (const float*)d_in[3];
  const float* att_dst = (const float*)d_in[4];
  const float* bias    = (const float*)d_in[5];

  const int nnodes = in_sizes[0] / HC;   // 50000
  const int E      = in_sizes[1] / 2;    // 800000
  const int nb     = (nnodes + 1023) / 1024;   // scan blocks (49)

  float* out = (float*)d_out;
  char* ws = (char*)d_ws;
  // Workspace (~30 MB), all segments 16B-aligned:
  unsigned short* h  = (unsigned short*)ws;                          // nnodes*256 bf16 (row-major)
  float* a_src = (float*)(ws + (size_t)nnodes * HC * 2);             // nnodes*4 f32
  float* a_dst = a_src + (size_t)nnodes * 4;
  unsigned short* Wt = (unsigned short*)(a_dst + (size_t)nnodes * 4); // 256*256 bf16
  int* deg    = (int*)((char*)Wt + 256 * 256 * 2);                   // nnodes
  int* rowptr = deg + nnodes;                                        // nnodes+1 (pad x4)
  int* cursor = rowptr + ((nnodes + 1 + 3) & ~3);                    // nnodes
  int* bsum   = cursor + nnodes;                                     // nb
  int* boff   = bsum + ((nb + 3) & ~3);                              // nb
  int* csr    = boff + ((nb + 3) & ~3);                              // E

  hipMemsetAsync(deg, 0, (size_t)nnodes * sizeof(int), stream);

  wt_kernel<<<256, 256, 0, stream>>>(W, Wt);

  gemm_mfma<<<(nnodes + BM - 1) / BM, 256, 0, stream>>>(
      x, Wt, att_src, att_dst, h, a_src, a_dst, nnodes);

  deg_count<<<(E + 255) / 256, 256, 0, stream>>>(ei, deg, E);
  scan_p1<<<nb, 256, 0, stream>>>(deg, bsum, nnodes);
  scan_p2<<<1, 1024, 0, stream>>>(bsum, boff, rowptr, nb, nnodes);
  scan_p3<<<nb, 256, 0, stream>>>(deg, boff, rowptr, cursor, nnodes);

  fill_csr<<<1024, 256, 0, stream>>>(ei, cursor, csr, E, nnodes);

  gather_kernel<<<(nnodes + 3) / 4, 256, 0, stream>>>(
      rowptr, csr, h, a_src, a_dst, bias, out, nnodes);
}